// Round 2
// baseline (361.543 us; speedup 1.0000x reference)
//
#include <hip/hip_runtime.h>
#include <hip/hip_bf16.h>
#include <math.h>

#define S_LEN 4096
#define DMODEL 2048
#define HEADD 128

typedef __attribute__((ext_vector_type(8))) short short8;
typedef __attribute__((ext_vector_type(4))) float floatx4;

__device__ __forceinline__ short f2bs(float f) {
  __hip_bfloat16 h = __float2bfloat16(f);
  short s; __builtin_memcpy(&s, &h, 2); return s;
}

// ---- Kernel 1: convert Wq,Wk,Wv (fp32 [128][2048] each) -> wc bf16 [384][2048]
__global__ __launch_bounds__(256) void convw_kernel(const float* __restrict__ wq,
                                                    const float* __restrict__ wk,
                                                    const float* __restrict__ wv,
                                                    short* __restrict__ wc) {
  const int per = 128 * 2048;
  int e = (blockIdx.x * blockDim.x + threadIdx.x) * 4;
  const float* src = (e < per) ? wq : (e < 2 * per) ? wk : wv;
  int off = e & (per - 1);
  float4 v = *(const float4*)(src + off);
  short4 r;
  r.x = f2bs(v.x); r.y = f2bs(v.y); r.z = f2bs(v.z); r.w = f2bs(v.w);
  *(short4*)(wc + e) = r;
}

// ---- Kernel 2: projection GEMM  C[8192][384] = X[8192][2048] @ Wc^T
__global__ __launch_bounds__(128) void proj_kernel(const float* __restrict__ x,
                                                   const short* __restrict__ wc,
                                                   short* __restrict__ qb,
                                                   short* __restrict__ kb,
                                                   short* __restrict__ vt) {
  const int w = threadIdx.x >> 6;
  const int lane = threadIdx.x & 63;
  const int lo = lane & 15, g = lane >> 4;
  const int m0 = blockIdx.x * 32 + w * 16;
  const int n0 = blockIdx.y * 192;

  const float* xrow = x + (size_t)(m0 + lo) * DMODEL;

  floatx4 acc[12];
#pragma unroll
  for (int t = 0; t < 12; ++t) acc[t] = floatx4{0.f, 0.f, 0.f, 0.f};

  for (int k = 0; k < DMODEL; k += 32) {
    const float* xp = xrow + k + g * 8;
    float4 a0 = *(const float4*)(xp);
    float4 a1 = *(const float4*)(xp + 4);
    short8 af;
    af[0] = f2bs(a0.x); af[1] = f2bs(a0.y); af[2] = f2bs(a0.z); af[3] = f2bs(a0.w);
    af[4] = f2bs(a1.x); af[5] = f2bs(a1.y); af[6] = f2bs(a1.z); af[7] = f2bs(a1.w);
#pragma unroll
    for (int t = 0; t < 12; ++t) {
      short8 bf = *(const short8*)(wc + (size_t)(n0 + t * 16 + lo) * DMODEL + k + g * 8);
      acc[t] = __builtin_amdgcn_mfma_f32_16x16x32_bf16(af, bf, acc[t], 0, 0, 0);
    }
  }

#pragma unroll
  for (int t = 0; t < 12; ++t) {
    int n = n0 + t * 16 + lo;
#pragma unroll
    for (int j = 0; j < 4; ++j) {
      int m = m0 + g * 4 + j;
      short bv = f2bs(acc[t][j]);
      if (n < HEADD) {
        qb[(size_t)m * HEADD + n] = bv;
      } else if (n < 2 * HEADD) {
        kb[(size_t)m * HEADD + (n - HEADD)] = bv;
      } else {
        int h = n - 2 * HEADD;
        int bb = m >> 12, s = m & (S_LEN - 1);
        vt[((size_t)bb * HEADD + h) * S_LEN + s] = bv;
      }
    }
  }
}

// ---- Kernel 3: dual flash attention + diff combine + RMSNorm
// block = 256 threads (4 waves). Each block: one 16-row q-tile; waves split KV
// 4-way (1024 each), block-level merge (m/l via LDS, acc via LDS atomicAdd).
__global__ __launch_bounds__(256, 4) void attn_kernel(const short* __restrict__ qb,
                                                      const short* __restrict__ kb,
                                                      const short* __restrict__ vt,
                                                      const float* __restrict__ lq1,
                                                      const float* __restrict__ lq2,
                                                      const float* __restrict__ lk1,
                                                      const float* __restrict__ lk2,
                                                      const float* __restrict__ rmsw,
                                                      float* __restrict__ out) {
  const int tid = threadIdx.x;
  const int w = tid >> 6;
  const int lane = tid & 63;
  const int lo = lane & 15, g = lane >> 4;
  const int b = blockIdx.x >> 8;
  const int qt = blockIdx.x & 255;

  __shared__ short p_lds[4][2][16][40];     // per-wave P transpose staging
  __shared__ float accbuf[2][16][132];      // merged unnormalized acc (stride 132: 2-way-max conflicts)
  __shared__ float merge_m[4][2][16];       // [wave][stream][row]
  __shared__ float merge_l[4][2][16];

  // lambda scalar (uniform; scalar-unit work)
  float a1 = 0.f, a2 = 0.f;
  for (int i = 0; i < 64; ++i) {
    a1 = fmaf(lq1[i], lk1[i], a1);
    a2 = fmaf(lq2[i], lk2[i], a2);
  }
  const float lam = __expf(a1) - __expf(a2) + 0.7836057665316245f;

  // Q fragments (A operand: row = lane&15, k = (lane>>4)*8 + j)
  const short* qrow = qb + (size_t)(b * S_LEN + qt * 16 + lo) * HEADD;
  const short8 q1f0 = *(const short8*)(qrow + g * 8);
  const short8 q1f1 = *(const short8*)(qrow + 32 + g * 8);
  const short8 q2f0 = *(const short8*)(qrow + 64 + g * 8);
  const short8 q2f1 = *(const short8*)(qrow + 96 + g * 8);

  floatx4 acc1[8], acc2[8];
#pragma unroll
  for (int n = 0; n < 8; ++n) {
    acc1[n] = floatx4{0.f, 0.f, 0.f, 0.f};
    acc2[n] = floatx4{0.f, 0.f, 0.f, 0.f};
  }
  float m1[4], l1[4], m2[4], l2[4];
#pragma unroll
  for (int j = 0; j < 4; ++j) { m1[j] = -1e30f; l1[j] = 0.f; m2[j] = -1e30f; l2[j] = 0.f; }

  const short* kbase = kb + (size_t)b * S_LEN * HEADD;
  const short* vbase = vt + (size_t)b * HEADD * S_LEN;

  const int kv_beg = w * 1024, kv_end = kv_beg + 1024;
  for (int kv = kv_beg; kv < kv_end; kv += 32) {
    floatx4 s1[2], s2[2];
#pragma unroll
    for (int t = 0; t < 2; ++t) {
      const short* krow = kbase + (size_t)(kv + t * 16 + lo) * HEADD;
      short8 k1f0 = *(const short8*)(krow + g * 8);
      short8 k1f1 = *(const short8*)(krow + 32 + g * 8);
      short8 k2f0 = *(const short8*)(krow + 64 + g * 8);
      short8 k2f1 = *(const short8*)(krow + 96 + g * 8);
      floatx4 z = floatx4{0.f, 0.f, 0.f, 0.f};
      floatx4 u1 = __builtin_amdgcn_mfma_f32_16x16x32_bf16(q1f0, k1f0, z, 0, 0, 0);
      s1[t] = __builtin_amdgcn_mfma_f32_16x16x32_bf16(q1f1, k1f1, u1, 0, 0, 0);
      floatx4 u2 = __builtin_amdgcn_mfma_f32_16x16x32_bf16(q2f0, k2f0, z, 0, 0, 0);
      s2[t] = __builtin_amdgcn_mfma_f32_16x16x32_bf16(q2f1, k2f1, u2, 0, 0, 0);
    }
#pragma unroll
    for (int t = 0; t < 2; ++t)
#pragma unroll
      for (int j = 0; j < 4; ++j) { s1[t][j] *= 0.125f; s2[t][j] *= 0.125f; }

    float mt1[4], mt2[4];
#pragma unroll
    for (int j = 0; j < 4; ++j) {
      mt1[j] = fmaxf(s1[0][j], s1[1][j]);
      mt2[j] = fmaxf(s2[0][j], s2[1][j]);
    }
#pragma unroll
    for (int d = 1; d < 16; d <<= 1)
#pragma unroll
      for (int j = 0; j < 4; ++j) {
        mt1[j] = fmaxf(mt1[j], __shfl_xor(mt1[j], d));
        mt2[j] = fmaxf(mt2[j], __shfl_xor(mt2[j], d));
      }

    float f1[4], f2[4], rs1[4], rs2[4];
#pragma unroll
    for (int j = 0; j < 4; ++j) {
      float nm1 = fmaxf(m1[j], mt1[j]);
      f1[j] = __expf(m1[j] - nm1); m1[j] = nm1;
      float p10 = __expf(s1[0][j] - nm1);
      float p11 = __expf(s1[1][j] - nm1);
      s1[0][j] = p10; s1[1][j] = p11; rs1[j] = p10 + p11;
      float nm2 = fmaxf(m2[j], mt2[j]);
      f2[j] = __expf(m2[j] - nm2); m2[j] = nm2;
      float p20 = __expf(s2[0][j] - nm2);
      float p21 = __expf(s2[1][j] - nm2);
      s2[0][j] = p20; s2[1][j] = p21; rs2[j] = p20 + p21;
    }
#pragma unroll
    for (int d = 1; d < 16; d <<= 1)
#pragma unroll
      for (int j = 0; j < 4; ++j) {
        rs1[j] += __shfl_xor(rs1[j], d);
        rs2[j] += __shfl_xor(rs2[j], d);
      }
#pragma unroll
    for (int j = 0; j < 4; ++j) {
      l1[j] = l1[j] * f1[j] + rs1[j];
      l2[j] = l2[j] * f2[j] + rs2[j];
    }
#pragma unroll
    for (int n = 0; n < 8; ++n)
#pragma unroll
      for (int j = 0; j < 4; ++j) { acc1[n][j] *= f1[j]; acc2[n][j] *= f2[j]; }

    // transpose P (D layout) -> A layout via per-wave LDS region, wave-synchronous.
    // WAR guard: prior iteration's reads must complete before overwriting.
    __builtin_amdgcn_sched_barrier(0);
    asm volatile("s_waitcnt lgkmcnt(0)" ::: "memory");
    __builtin_amdgcn_sched_barrier(0);
#pragma unroll
    for (int t = 0; t < 2; ++t)
#pragma unroll
      for (int j = 0; j < 4; ++j) {
        p_lds[w][0][g * 4 + j][t * 16 + lo] = f2bs(s1[t][j]);
        p_lds[w][1][g * 4 + j][t * 16 + lo] = f2bs(s2[t][j]);
      }
    // RAW guard: writes visible before cross-lane reads.
    __builtin_amdgcn_sched_barrier(0);
    asm volatile("s_waitcnt lgkmcnt(0)" ::: "memory");
    __builtin_amdgcn_sched_barrier(0);
    short8 pa1 = *(const short8*)&p_lds[w][0][lo][g * 8];
    short8 pa2 = *(const short8*)&p_lds[w][1][lo][g * 8];

#pragma unroll
    for (int n = 0; n < 8; ++n) {
      short8 vf = *(const short8*)(vbase + (size_t)(n * 16 + lo) * S_LEN + kv + g * 8);
      acc1[n] = __builtin_amdgcn_mfma_f32_16x16x32_bf16(pa1, vf, acc1[n], 0, 0, 0);
      acc2[n] = __builtin_amdgcn_mfma_f32_16x16x32_bf16(pa2, vf, acc2[n], 0, 0, 0);
    }
  }

  // ---- block-level merge of the 4 KV-chunk partials ----
  for (int t = tid; t < 2 * 16 * 132; t += 256) ((float*)accbuf)[t] = 0.f;
  if (lo == 0) {
#pragma unroll
    for (int j = 0; j < 4; ++j) {
      merge_m[w][0][g * 4 + j] = m1[j];
      merge_l[w][0][g * 4 + j] = l1[j];
      merge_m[w][1][g * 4 + j] = m2[j];
      merge_l[w][1][g * 4 + j] = l2[j];
    }
  }
  __syncthreads();

  float C1[4], C2[4];
#pragma unroll
  for (int j = 0; j < 4; ++j) {
    int r = g * 4 + j;
    float M1 = -1e30f, M2 = -1e30f;
#pragma unroll
    for (int w2 = 0; w2 < 4; ++w2) {
      M1 = fmaxf(M1, merge_m[w2][0][r]);
      M2 = fmaxf(M2, merge_m[w2][1][r]);
    }
    C1[j] = __expf(m1[j] - M1);
    C2[j] = __expf(m2[j] - M2);
  }
#pragma unroll
  for (int n = 0; n < 8; ++n)
#pragma unroll
    for (int j = 0; j < 4; ++j) {
      atomicAdd(&accbuf[0][g * 4 + j][n * 16 + lo], acc1[n][j] * C1[j]);
      atomicAdd(&accbuf[1][g * 4 + j][n * 16 + lo], acc2[n][j] * C2[j]);
    }
  __syncthreads();

  if (w == 0) {
    const int r = lane >> 2;        // row 0..15
    const int q = lane & 3;         // 32-col quarter
    float M1 = -1e30f, M2 = -1e30f;
#pragma unroll
    for (int w2 = 0; w2 < 4; ++w2) {
      M1 = fmaxf(M1, merge_m[w2][0][r]);
      M2 = fmaxf(M2, merge_m[w2][1][r]);
    }
    float L1 = 0.f, L2 = 0.f;
#pragma unroll
    for (int w2 = 0; w2 < 4; ++w2) {
      L1 += merge_l[w2][0][r] * __expf(merge_m[w2][0][r] - M1);
      L2 += merge_l[w2][1][r] * __expf(merge_m[w2][1][r] - M2);
    }
    const float iL1 = 1.f / L1, iL2 = 1.f / L2;

    float4 v1[8];
    float ssq = 0.f;
#pragma unroll
    for (int i = 0; i < 8; ++i) {
      float4 o1 = *(const float4*)&accbuf[0][r][q * 32 + i * 4];
      float4 o2 = *(const float4*)&accbuf[1][r][q * 32 + i * 4];
      float4 v;
      v.x = o1.x * iL1 - lam * (o2.x * iL2);
      v.y = o1.y * iL1 - lam * (o2.y * iL2);
      v.z = o1.z * iL1 - lam * (o2.z * iL2);
      v.w = o1.w * iL1 - lam * (o2.w * iL2);
      ssq += v.x * v.x + v.y * v.y + v.z * v.z + v.w * v.w;
      v1[i] = v;
    }
    ssq += __shfl_xor(ssq, 1);
    ssq += __shfl_xor(ssq, 2);
    const float rr = rsqrtf(ssq * (1.f / 128.f) + 1.1920928955078125e-07f);

    float* ob = out + ((size_t)b * S_LEN + qt * 16 + r) * HEADD + q * 32;
#pragma unroll
    for (int i = 0; i < 8; ++i) {
      float4 wv4 = *(const float4*)(rmsw + q * 32 + i * 4);
      float4 s;
      s.x = 0.21639423346837554f * v1[i].x * rr * wv4.x;
      s.y = 0.21639423346837554f * v1[i].y * rr * wv4.y;
      s.z = 0.21639423346837554f * v1[i].z * rr * wv4.z;
      s.w = 0.21639423346837554f * v1[i].w * rr * wv4.w;
      *(float4*)(ob + i * 4) = s;
    }
  }
}

extern "C" void kernel_launch(void* const* d_in, const int* in_sizes, int n_in,
                              void* d_out, int out_size, void* d_ws, size_t ws_size,
                              hipStream_t stream) {
  const float* x   = (const float*)d_in[0];
  const float* wq  = (const float*)d_in[1];
  const float* wk  = (const float*)d_in[2];
  const float* wv  = (const float*)d_in[3];
  const float* lq1 = (const float*)d_in[4];
  const float* lq2 = (const float*)d_in[5];
  const float* lk1 = (const float*)d_in[6];
  const float* lk2 = (const float*)d_in[7];
  const float* rw  = (const float*)d_in[8];
  float* out = (float*)d_out;

  char* ws = (char*)d_ws;
  short* qb = (short*)(ws);                    // 2 MB
  short* kb = (short*)(ws + (2u << 20));       // 2 MB
  short* vt = (short*)(ws + (4u << 20));       // 2 MB (V transposed [b][h][s])
  short* wc = (short*)(ws + (6u << 20));       // 1.5 MB

  convw_kernel<<<768, 256, 0, stream>>>(wq, wk, wv, wc);
  proj_kernel<<<dim3(256, 2), 128, 0, stream>>>(x, wc, qb, kb, vt);
  attn_kernel<<<512, 256, 0, stream>>>(qb, kb, vt, lq1, lq2, lk1, lk2, rw, out);
}

// Round 3
// 291.309 us; speedup vs baseline: 1.2411x; 1.2411x over previous
//
#include <hip/hip_runtime.h>
#include <hip/hip_bf16.h>
#include <math.h>

#define S_LEN 4096
#define DMODEL 2048
#define HEADD 128

typedef __attribute__((ext_vector_type(8))) short short8;
typedef __attribute__((ext_vector_type(4))) float floatx4;

__device__ __forceinline__ short f2bs(float f) {
  __hip_bfloat16 h = __float2bfloat16(f);
  short s; __builtin_memcpy(&s, &h, 2); return s;
}

// ---- Kernel 1: convert Wq,Wk,Wv (fp32 [128][2048] each) -> wc bf16 [384][2048]
__global__ __launch_bounds__(256) void convw_kernel(const float* __restrict__ wq,
                                                    const float* __restrict__ wk,
                                                    const float* __restrict__ wv,
                                                    short* __restrict__ wc) {
  const int per = 128 * 2048;
  int e = (blockIdx.x * blockDim.x + threadIdx.x) * 4;
  const float* src = (e < per) ? wq : (e < 2 * per) ? wk : wv;
  int off = e & (per - 1);
  float4 v = *(const float4*)(src + off);
  short4 r;
  r.x = f2bs(v.x); r.y = f2bs(v.y); r.z = f2bs(v.z); r.w = f2bs(v.w);
  *(short4*)(wc + e) = r;
}

// ---- Kernel 2: projection GEMM  C[8192][384] = X[8192][2048] @ Wc^T
__global__ __launch_bounds__(128) void proj_kernel(const float* __restrict__ x,
                                                   const short* __restrict__ wc,
                                                   short* __restrict__ qb,
                                                   short* __restrict__ kb,
                                                   short* __restrict__ vt) {
  const int w = threadIdx.x >> 6;
  const int lane = threadIdx.x & 63;
  const int lo = lane & 15, g = lane >> 4;
  const int m0 = blockIdx.x * 32 + w * 16;
  const int n0 = blockIdx.y * 192;

  const float* xrow = x + (size_t)(m0 + lo) * DMODEL;

  floatx4 acc[12];
#pragma unroll
  for (int t = 0; t < 12; ++t) acc[t] = floatx4{0.f, 0.f, 0.f, 0.f};

  for (int k = 0; k < DMODEL; k += 32) {
    const float* xp = xrow + k + g * 8;
    float4 a0 = *(const float4*)(xp);
    float4 a1 = *(const float4*)(xp + 4);
    short8 af;
    af[0] = f2bs(a0.x); af[1] = f2bs(a0.y); af[2] = f2bs(a0.z); af[3] = f2bs(a0.w);
    af[4] = f2bs(a1.x); af[5] = f2bs(a1.y); af[6] = f2bs(a1.z); af[7] = f2bs(a1.w);
#pragma unroll
    for (int t = 0; t < 12; ++t) {
      short8 bf = *(const short8*)(wc + (size_t)(n0 + t * 16 + lo) * DMODEL + k + g * 8);
      acc[t] = __builtin_amdgcn_mfma_f32_16x16x32_bf16(af, bf, acc[t], 0, 0, 0);
    }
  }

#pragma unroll
  for (int t = 0; t < 12; ++t) {
    int n = n0 + t * 16 + lo;
#pragma unroll
    for (int j = 0; j < 4; ++j) {
      int m = m0 + g * 4 + j;
      short bv = f2bs(acc[t][j]);
      if (n < HEADD) {
        qb[(size_t)m * HEADD + n] = bv;
      } else if (n < 2 * HEADD) {
        kb[(size_t)m * HEADD + (n - HEADD)] = bv;
      } else {
        int h = n - 2 * HEADD;
        int bb = m >> 12, s = m & (S_LEN - 1);
        vt[((size_t)bb * HEADD + h) * S_LEN + s] = bv;
      }
    }
  }
}

// ---- Kernel 3: dual flash attention + diff combine + RMSNorm
// block = 256 threads (4 waves). Each block: one 16-row q-tile; waves split KV
// 4-way (1024 each), block-level merge (m/l via LDS, acc via LDS atomicAdd).
// launch_bounds min-waves = 2 (NOT 4): the loop state (64 acc fp32 + 8 frags)
// needs ~130-160 VGPR; capping at 128 spilled to scratch (R2: WRITE_SIZE 39MB).
__global__ __launch_bounds__(256, 2) void attn_kernel(const short* __restrict__ qb,
                                                      const short* __restrict__ kb,
                                                      const short* __restrict__ vt,
                                                      const float* __restrict__ lq1,
                                                      const float* __restrict__ lq2,
                                                      const float* __restrict__ lk1,
                                                      const float* __restrict__ lk2,
                                                      const float* __restrict__ rmsw,
                                                      float* __restrict__ out) {
  const int tid = threadIdx.x;
  const int w = tid >> 6;
  const int lane = tid & 63;
  const int lo = lane & 15, g = lane >> 4;
  const int b = blockIdx.x >> 8;
  const int qt = blockIdx.x & 255;

  __shared__ short p_lds[4][2][16][40];     // per-wave P transpose staging
  __shared__ float accbuf[2][16][132];      // merged unnormalized acc
  __shared__ float merge_m[4][2][16];       // [wave][stream][row]
  __shared__ float merge_l[4][2][16];

  // lambda scalar (uniform; scalar-unit work)
  float a1 = 0.f, a2 = 0.f;
  for (int i = 0; i < 64; ++i) {
    a1 = fmaf(lq1[i], lk1[i], a1);
    a2 = fmaf(lq2[i], lk2[i], a2);
  }
  const float lam = __expf(a1) - __expf(a2) + 0.7836057665316245f;

  // Q fragments (A operand: row = lane&15, k = (lane>>4)*8 + j)
  const short* qrow = qb + (size_t)(b * S_LEN + qt * 16 + lo) * HEADD;
  const short8 q1f0 = *(const short8*)(qrow + g * 8);
  const short8 q1f1 = *(const short8*)(qrow + 32 + g * 8);
  const short8 q2f0 = *(const short8*)(qrow + 64 + g * 8);
  const short8 q2f1 = *(const short8*)(qrow + 96 + g * 8);

  floatx4 acc1[8], acc2[8];
#pragma unroll
  for (int n = 0; n < 8; ++n) {
    acc1[n] = floatx4{0.f, 0.f, 0.f, 0.f};
    acc2[n] = floatx4{0.f, 0.f, 0.f, 0.f};
  }
  float m1[4], l1[4], m2[4], l2[4];
#pragma unroll
  for (int j = 0; j < 4; ++j) { m1[j] = -1e30f; l1[j] = 0.f; m2[j] = -1e30f; l2[j] = 0.f; }

  const short* kbase = kb + (size_t)b * S_LEN * HEADD;
  const short* vbase = vt + (size_t)b * HEADD * S_LEN;

  const int kv_beg = w * 1024, kv_end = kv_beg + 1024;
  for (int kv = kv_beg; kv < kv_end; kv += 32) {
    floatx4 s1[2], s2[2];
#pragma unroll
    for (int t = 0; t < 2; ++t) {
      const short* krow = kbase + (size_t)(kv + t * 16 + lo) * HEADD;
      short8 k1f0 = *(const short8*)(krow + g * 8);
      short8 k1f1 = *(const short8*)(krow + 32 + g * 8);
      short8 k2f0 = *(const short8*)(krow + 64 + g * 8);
      short8 k2f1 = *(const short8*)(krow + 96 + g * 8);
      floatx4 z = floatx4{0.f, 0.f, 0.f, 0.f};
      floatx4 u1 = __builtin_amdgcn_mfma_f32_16x16x32_bf16(q1f0, k1f0, z, 0, 0, 0);
      s1[t] = __builtin_amdgcn_mfma_f32_16x16x32_bf16(q1f1, k1f1, u1, 0, 0, 0);
      floatx4 u2 = __builtin_amdgcn_mfma_f32_16x16x32_bf16(q2f0, k2f0, z, 0, 0, 0);
      s2[t] = __builtin_amdgcn_mfma_f32_16x16x32_bf16(q2f1, k2f1, u2, 0, 0, 0);
    }
#pragma unroll
    for (int t = 0; t < 2; ++t)
#pragma unroll
      for (int j = 0; j < 4; ++j) { s1[t][j] *= 0.125f; s2[t][j] *= 0.125f; }

    float mt1[4], mt2[4];
#pragma unroll
    for (int j = 0; j < 4; ++j) {
      mt1[j] = fmaxf(s1[0][j], s1[1][j]);
      mt2[j] = fmaxf(s2[0][j], s2[1][j]);
    }
#pragma unroll
    for (int d = 1; d < 16; d <<= 1)
#pragma unroll
      for (int j = 0; j < 4; ++j) {
        mt1[j] = fmaxf(mt1[j], __shfl_xor(mt1[j], d));
        mt2[j] = fmaxf(mt2[j], __shfl_xor(mt2[j], d));
      }

    float f1[4], f2[4], rs1[4], rs2[4];
#pragma unroll
    for (int j = 0; j < 4; ++j) {
      float nm1 = fmaxf(m1[j], mt1[j]);
      f1[j] = __expf(m1[j] - nm1); m1[j] = nm1;
      float p10 = __expf(s1[0][j] - nm1);
      float p11 = __expf(s1[1][j] - nm1);
      s1[0][j] = p10; s1[1][j] = p11; rs1[j] = p10 + p11;
      float nm2 = fmaxf(m2[j], mt2[j]);
      f2[j] = __expf(m2[j] - nm2); m2[j] = nm2;
      float p20 = __expf(s2[0][j] - nm2);
      float p21 = __expf(s2[1][j] - nm2);
      s2[0][j] = p20; s2[1][j] = p21; rs2[j] = p20 + p21;
    }
#pragma unroll
    for (int d = 1; d < 16; d <<= 1)
#pragma unroll
      for (int j = 0; j < 4; ++j) {
        rs1[j] += __shfl_xor(rs1[j], d);
        rs2[j] += __shfl_xor(rs2[j], d);
      }
#pragma unroll
    for (int j = 0; j < 4; ++j) {
      l1[j] = l1[j] * f1[j] + rs1[j];
      l2[j] = l2[j] * f2[j] + rs2[j];
    }
#pragma unroll
    for (int n = 0; n < 8; ++n)
#pragma unroll
      for (int j = 0; j < 4; ++j) { acc1[n][j] *= f1[j]; acc2[n][j] *= f2[j]; }

    // transpose P (D layout) -> A layout via per-wave LDS region, wave-synchronous.
    __builtin_amdgcn_sched_barrier(0);
    asm volatile("s_waitcnt lgkmcnt(0)" ::: "memory");
    __builtin_amdgcn_sched_barrier(0);
#pragma unroll
    for (int t = 0; t < 2; ++t)
#pragma unroll
      for (int j = 0; j < 4; ++j) {
        p_lds[w][0][g * 4 + j][t * 16 + lo] = f2bs(s1[t][j]);
        p_lds[w][1][g * 4 + j][t * 16 + lo] = f2bs(s2[t][j]);
      }
    __builtin_amdgcn_sched_barrier(0);
    asm volatile("s_waitcnt lgkmcnt(0)" ::: "memory");
    __builtin_amdgcn_sched_barrier(0);
    short8 pa1 = *(const short8*)&p_lds[w][0][lo][g * 8];
    short8 pa2 = *(const short8*)&p_lds[w][1][lo][g * 8];

#pragma unroll
    for (int n = 0; n < 8; ++n) {
      short8 vf = *(const short8*)(vbase + (size_t)(n * 16 + lo) * S_LEN + kv + g * 8);
      acc1[n] = __builtin_amdgcn_mfma_f32_16x16x32_bf16(pa1, vf, acc1[n], 0, 0, 0);
      acc2[n] = __builtin_amdgcn_mfma_f32_16x16x32_bf16(pa2, vf, acc2[n], 0, 0, 0);
    }
  }

  // ---- block-level merge of the 4 KV-chunk partials ----
  for (int t = tid; t < 2 * 16 * 132; t += 256) ((float*)accbuf)[t] = 0.f;
  if (lo == 0) {
#pragma unroll
    for (int j = 0; j < 4; ++j) {
      merge_m[w][0][g * 4 + j] = m1[j];
      merge_l[w][0][g * 4 + j] = l1[j];
      merge_m[w][1][g * 4 + j] = m2[j];
      merge_l[w][1][g * 4 + j] = l2[j];
    }
  }
  __syncthreads();

  float C1[4], C2[4];
#pragma unroll
  for (int j = 0; j < 4; ++j) {
    int r = g * 4 + j;
    float M1 = -1e30f, M2 = -1e30f;
#pragma unroll
    for (int w2 = 0; w2 < 4; ++w2) {
      M1 = fmaxf(M1, merge_m[w2][0][r]);
      M2 = fmaxf(M2, merge_m[w2][1][r]);
    }
    C1[j] = __expf(m1[j] - M1);
    C2[j] = __expf(m2[j] - M2);
  }
#pragma unroll
  for (int n = 0; n < 8; ++n)
#pragma unroll
    for (int j = 0; j < 4; ++j) {
      atomicAdd(&accbuf[0][g * 4 + j][n * 16 + lo], acc1[n][j] * C1[j]);
      atomicAdd(&accbuf[1][g * 4 + j][n * 16 + lo], acc2[n][j] * C2[j]);
    }
  __syncthreads();

  if (w == 0) {
    const int r = lane >> 2;        // row 0..15
    const int q = lane & 3;         // 32-col quarter
    float M1 = -1e30f, M2 = -1e30f;
#pragma unroll
    for (int w2 = 0; w2 < 4; ++w2) {
      M1 = fmaxf(M1, merge_m[w2][0][r]);
      M2 = fmaxf(M2, merge_m[w2][1][r]);
    }
    float L1 = 0.f, L2 = 0.f;
#pragma unroll
    for (int w2 = 0; w2 < 4; ++w2) {
      L1 += merge_l[w2][0][r] * __expf(merge_m[w2][0][r] - M1);
      L2 += merge_l[w2][1][r] * __expf(merge_m[w2][1][r] - M2);
    }
    const float iL1 = 1.f / L1, iL2 = 1.f / L2;

    float4 v1[8];
    float ssq = 0.f;
#pragma unroll
    for (int i = 0; i < 8; ++i) {
      float4 o1 = *(const float4*)&accbuf[0][r][q * 32 + i * 4];
      float4 o2 = *(const float4*)&accbuf[1][r][q * 32 + i * 4];
      float4 v;
      v.x = o1.x * iL1 - lam * (o2.x * iL2);
      v.y = o1.y * iL1 - lam * (o2.y * iL2);
      v.z = o1.z * iL1 - lam * (o2.z * iL2);
      v.w = o1.w * iL1 - lam * (o2.w * iL2);
      ssq += v.x * v.x + v.y * v.y + v.z * v.z + v.w * v.w;
      v1[i] = v;
    }
    ssq += __shfl_xor(ssq, 1);
    ssq += __shfl_xor(ssq, 2);
    const float rr = rsqrtf(ssq * (1.f / 128.f) + 1.1920928955078125e-07f);

    float* ob = out + ((size_t)b * S_LEN + qt * 16 + r) * HEADD + q * 32;
#pragma unroll
    for (int i = 0; i < 8; ++i) {
      float4 wv4 = *(const float4*)(rmsw + q * 32 + i * 4);
      float4 s;
      s.x = 0.21639423346837554f * v1[i].x * rr * wv4.x;
      s.y = 0.21639423346837554f * v1[i].y * rr * wv4.y;
      s.z = 0.21639423346837554f * v1[i].z * rr * wv4.z;
      s.w = 0.21639423346837554f * v1[i].w * rr * wv4.w;
      *(float4*)(ob + i * 4) = s;
    }
  }
}

extern "C" void kernel_launch(void* const* d_in, const int* in_sizes, int n_in,
                              void* d_out, int out_size, void* d_ws, size_t ws_size,
                              hipStream_t stream) {
  const float* x   = (const float*)d_in[0];
  const float* wq  = (const float*)d_in[1];
  const float* wk  = (const float*)d_in[2];
  const float* wv  = (const float*)d_in[3];
  const float* lq1 = (const float*)d_in[4];
  const float* lq2 = (const float*)d_in[5];
  const float* lk1 = (const float*)d_in[6];
  const float* lk2 = (const float*)d_in[7];
  const float* rw  = (const float*)d_in[8];
  float* out = (float*)d_out;

  char* ws = (char*)d_ws;
  short* qb = (short*)(ws);                    // 2 MB
  short* kb = (short*)(ws + (2u << 20));       // 2 MB
  short* vt = (short*)(ws + (4u << 20));       // 2 MB (V transposed [b][h][s])
  short* wc = (short*)(ws + (6u << 20));       // 1.5 MB

  convw_kernel<<<768, 256, 0, stream>>>(wq, wk, wv, wc);
  proj_kernel<<<dim3(256, 2), 128, 0, stream>>>(x, wc, qb, kb, vt);
  attn_kernel<<<512, 256, 0, stream>>>(qb, kb, vt, lq1, lq2, lk1, lk2, rw, out);
}